// Round 13
// baseline (231.480 us; speedup 1.0000x reference)
//
#include <hip/hip_runtime.h>

// FFB encoder fused kernel, MI355X (gfx950). Round 23.
//  R22 post-mortem: unroll-1 ~flat (152.7 med; I$ theory falsified). BUT the
//  ceiling arithmetic exposed: VALU-busy 135K + matrix-busy 124K + LDS ~=
//  wall 365K cyc/SIMD -- the separate pipes NEVER overlap. Pipe-max floor is
//  ~150K (~60us); measured wall is the SERIAL SUM. Diagnosis: PHASE-LOCKED
//  CONVOY -- the 3 co-resident blocks launch simultaneously, run identical
//  code, so all alternate {GEMM1: matrix busy/VALU idle} <-> {epilogue: VALU
//  busy/matrix idle} in lockstep forever (simultaneous completion re-locks
//  successors). Explains the whole session: occupancy/barrier changes moved
//  nothing (convoy unaffected); only VALU-work deletion (fract, bias) helped
//  (shortens a convoy phase).
//  R23: break the convoy -- per-block start skew of (key%3)*~2880 cyc
//  (~1/3 of the ~8.3K-cyc layer period) via s_sleep at kernel entry.
//  key = (bid + (bid>>8)) % 3 staggers co-residents under both linear and
//  XCD-round-robin dispatch. Pure scalar delay; tail cost <= ~2.4us.
//  A/B: convoy right -> MfmaUtil AND VALUBusy BOTH rise, dur 125-140us;
//  wrong -> flat 152-156 -> declare ceiling next round.
//  Tripwires: WRITE 32.77MB / FETCH 14.5MB / VGPR ~76 / absmax 0.0625.
//  Kept from R22 (best): #pragma unroll 1 l-loop, bias-in-C1-init, operand-
//  swapped GEMM1/grid, ring-4/dist-3 both GEMMs, G-hoist, raw v_sin,
//  packed-b64 stores, 32x32x16 head, stride-264 LDS, (256,3), 2 barriers/layer.

#define TM 64
#define XSTRIDE 264
#define GSTRIDE 48
#define K5 0.79577471545947667f         // 5/(2*pi)

typedef __attribute__((ext_vector_type(8))) _Float16 v8h;
typedef __attribute__((ext_vector_type(4))) _Float16 v4h;
typedef __attribute__((ext_vector_type(4))) float v4f;
typedef __attribute__((ext_vector_type(16))) float v16f;

#define MFMA32H(a, b, c) __builtin_amdgcn_mfma_f32_32x32x16_f16(a, b, c, 0, 0, 0)

// Raw v_sin_f32: input in revolutions; HW range reduction covers |u| << 256.
__device__ __forceinline__ float sin_hw(float u) {
    return __builtin_amdgcn_sinf(u);
}

__device__ __forceinline__ short f16s(float x) {      // RNE f32->f16
    _Float16 hh = (_Float16)x;
    return __builtin_bit_cast(short, hh);
}

// ---------------- weight packing ----------------
// wh   f16: [l][kb16][nt8][lane64][8]  (327680 shorts), scaled by K5
// whh  f16: [l][kb16][nt2][lane64][8]  (81920 shorts),  scaled by K5  (32-col tiles)
// gf   f16: [l][nt8][lane64][8]        (20480 shorts),  ffnA*2^(l-1)
// bhs  f32: [l][256]  = bh*K5          (1280 floats)
// bhhs f32: [l][64]   = bhh*K5         (320 floats)
__global__ __launch_bounds__(256) void ffb_pack(
    const float* __restrict__ Wh, const float* __restrict__ Whh,
    const float* __restrict__ ffnA,
    const float* __restrict__ bh, const float* __restrict__ bhh,
    short* __restrict__ wh, short* __restrict__ whh, short* __restrict__ gf,
    float* __restrict__ bhs, float* __restrict__ bhhs)
{
    int t = blockIdx.x * 256 + threadIdx.x;
    if (t < 40960) {                       // (l, kb, nt, lane)
        int lane = t & 63, nt = (t >> 6) & 7, kb = (t >> 9) & 15, l = t >> 13;
        int n = nt * 32 + (lane & 31);
        int k0 = kb * 16 + (lane >> 5) * 8;
        short hs[8];
        #pragma unroll
        for (int jj = 0; jj < 8; jj++)
            hs[jj] = f16s(Wh[(l * 256 + k0 + jj) * 256 + n] * K5);
        *(v8h*)(wh + t * 8) = *(v8h*)hs;
    } else if (t < 51200) {
        int t2 = t - 40960;                // (l, kb16, nt2, lane)
        int lane = t2 & 63, nt = (t2 >> 6) & 1, kb = (t2 >> 7) & 15, l = t2 >> 11;
        int n = nt * 32 + (lane & 31);
        int k0 = kb * 16 + (lane >> 5) * 8;
        short hs[8];
        #pragma unroll
        for (int jj = 0; jj < 8; jj++)
            hs[jj] = f16s(Whh[(l * 256 + k0 + jj) * 64 + n] * K5);
        *(v8h*)(whh + t2 * 8) = *(v8h*)hs;
    } else if (t < 53760) {
        int t3 = t - 51200;                // (l, nt, lane)
        int lane = t3 & 63, nt = (t3 >> 6) & 7, l = t3 >> 9;
        int n = nt * 32 + (lane & 31);
        const float sc = 0.5f * (float)(1 << l);       // 2^(l-1), exact
        short hs[8];
        #pragma unroll
        for (int jj = 0; jj < 8; jj++)
            hs[jj] = f16s(ffnA[(l * 8 + jj) * 256 + n] * sc);
        *(v8h*)(gf + t3 * 8) = *(v8h*)hs;
    } else if (t < 55040) {
        int t4 = t - 53760;
        bhs[t4] = bh[t4] * K5;
    } else if (t < 55360) {
        int t5 = t - 55040;
        bhhs[t5] = bhh[t5] * K5;
    }
}

// ---------------- main fused kernel ----------------
__global__ __launch_bounds__(256, 3) void ffb_main(
    const float* __restrict__ pos, const float* __restrict__ gfeat,
    const float* __restrict__ W0, const float* __restrict__ b0,
    const float* __restrict__ bhs, const float* __restrict__ bhhs,
    const short* __restrict__ wh, const short* __restrict__ whh,
    const short* __restrict__ gf,
    float* __restrict__ out)
{
    __shared__ __align__(16) short s_x[TM * XSTRIDE];   // f16  (33792 B)
    __shared__ __align__(16) short s_g[TM * GSTRIDE];   // f16  (6144 B)

    // ---- convoy-breaking start skew: (key%3) * ~2880 cyc of s_sleep ----
    {
        const unsigned bid = blockIdx.x;
        const int skew = (int)((bid + (bid >> 8)) % 3u) * 3;
        for (int i = 0; i < skew; ++i)
            __builtin_amdgcn_s_sleep(15);   // ~960 cyc each
    }

    const int tid = threadIdx.x;
    const int row0 = blockIdx.x * TM;
    const int lane = tid & 63;
    const int w = tid >> 6;
    const int m32 = lane & 31;
    const int h = lane >> 5;
    const int mq = w >> 1;                 // head-GEMM quadrant row-tile
    const int tq = w & 1;                  // head-GEMM quadrant col-tile

    for (int k2 = tid; k2 < TM * 40; k2 += 256) {
        int r = k2 / 40, f = k2 % 40;
        s_g[r * GSTRIDE + f] = f16s(gfeat[row0 * 40 + k2]);
    }

    // layer 0: x = sin(5*(pos@W0 + b0)); wave w = rows w*16..+15,
    // thread = cols 4*lane..+3; f32 math; packed b64 stores.
    {
        const int c0 = 4 * lane;
        const int r0 = w * 16;
        float w0c[3][4], bq[4];
        #pragma unroll
        for (int j = 0; j < 4; j++) {
            w0c[0][j] = W0[c0 + j];
            w0c[1][j] = W0[256 + c0 + j];
            w0c[2][j] = W0[512 + c0 + j];
            bq[j] = b0[c0 + j];
        }
        #pragma unroll 4
        for (int r = 0; r < 16; r++) {
            const float p0 = pos[(row0 + r0 + r) * 3 + 0];   // wave-uniform
            const float p1 = pos[(row0 + r0 + r) * 3 + 1];
            const float p2 = pos[(row0 + r0 + r) * 3 + 2];
            v4h pv;
            #pragma unroll
            for (int j = 0; j < 4; j++) {
                float d = p0 * w0c[0][j] + p1 * w0c[1][j] + p2 * w0c[2][j] + bq[j];
                pv[j] = (_Float16)sin_hw(d * K5);
            }
            *(v4h*)(s_x + (r0 + r) * XSTRIDE + c0) = pv;
        }
    }
    __syncthreads();

    float cout[16];
    #pragma unroll
    for (int r = 0; r < 16; r++) cout[r] = 0.f;

    const int a1off0 = m32 * XSTRIDE + h * 8;            // x-row tile 0, + kb*16
    const int a1off1 = (32 + m32) * XSTRIDE + h * 8;     // x-row tile 1

    // NOT unrolled: keep the loop body small (R22).
    #pragma unroll 1
    for (int l = 0; l < 5; l++) {
        // ---- C1 init with bias (K5-prescaled; R12-proven at 256,3) ----
        // wcol(reg r, h) = w*64 + tt*32 + 8*(r>>2) + 4*h + (r&3)
        v16f C1[2][2];
        {
            const float* bl = bhs + l * 256 + w * 64 + h * 4;
            #pragma unroll
            for (int tt = 0; tt < 2; tt++)
                #pragma unroll
                for (int rq = 0; rq < 4; rq++) {
                    v4f b = *(const v4f*)(bl + tt * 32 + rq * 8);
                    #pragma unroll
                    for (int j = 0; j < 4; j++) {
                        C1[0][tt][rq * 4 + j] = b[j];
                        C1[1][tt][rq * 4 + j] = b[j];
                    }
                }
        }

        // ---- GEMM1 (swapped): wh = A, x = B; ring-4/dist-3 ----
        {
            const short* bp = wh + l * 65536 + (2 * w) * 512 + lane * 8;
            v8h rb0[4], rb1[4];
            #pragma unroll
            for (int p = 0; p < 3; p++) {
                rb0[p] = *(const v8h*)(bp + p * 4096);
                rb1[p] = *(const v8h*)(bp + p * 4096 + 512);
            }
            #pragma unroll
            for (int kb = 0; kb < 16; kb++) {
                if (kb + 3 < 16) {
                    rb0[(kb + 3) & 3] = *(const v8h*)(bp + (kb + 3) * 4096);
                    rb1[(kb + 3) & 3] = *(const v8h*)(bp + (kb + 3) * 4096 + 512);
                }
                v8h a0 = *(const v8h*)&s_x[a1off0 + kb * 16];
                v8h a1 = *(const v8h*)&s_x[a1off1 + kb * 16];
                v8h bc0 = rb0[kb & 3], bc1 = rb1[kb & 3];
                C1[0][0] = MFMA32H(bc0, a0, C1[0][0]);
                C1[0][1] = MFMA32H(bc1, a0, C1[0][1]);
                C1[1][0] = MFMA32H(bc0, a1, C1[1][0]);
                C1[1][1] = MFMA32H(bc1, a1, C1[1][1]);
            }
        }
        __syncthreads();   // all waves done reading x_l

        // ---- epilogue: x = sin(C1) + sin(G); per m-tile, BOTH G MFMAs
        //      issued before sin consumption; packed b64 stores ----
        {
            v8h gb0 = *(const v8h*)(gf + ((l * 8 + w * 2 + 0) * 64 + lane) * 8);
            v8h gb1 = *(const v8h*)(gf + ((l * 8 + w * 2 + 1) * 64 + lane) * 8);
            #pragma unroll
            for (int m = 0; m < 2; m++) {
                v8h ga = *(const v8h*)&s_g[(m * 32 + m32) * GSTRIDE + l * 8];
                v16f Z = {};
                v16f G0 = MFMA32H(gb0, ga, Z);
                v16f G1 = MFMA32H(gb1, ga, Z);
                const int rowb = (m * 32 + m32) * XSTRIDE;
                #pragma unroll
                for (int tt = 0; tt < 2; tt++) {
                    const int cb = rowb + w * 64 + tt * 32 + h * 4;
                    #pragma unroll
                    for (int rq = 0; rq < 4; rq++) {
                        v4h pv;
                        #pragma unroll
                        for (int j = 0; j < 4; j++) {
                            float gv = tt ? G1[rq * 4 + j] : G0[rq * 4 + j];
                            pv[j] = (_Float16)(sin_hw(C1[m][tt][rq * 4 + j])
                                             + sin_hw(gv));
                        }
                        *(v4h*)(s_x + cb + rq * 8) = pv;    // 8B aligned
                    }
                }
            }
        }
        __syncthreads();   // new x visible

        // ---- head GEMM, 32x32x16: wave = quadrant (mq,tq); whh 32-col
        //      tiles = B; ring-4/dist-3 ----
        {
            const float b2 = bhhs[l * 64 + tq * 32 + m32];
            v16f C2;
            #pragma unroll
            for (int r = 0; r < 16; r++) C2[r] = b2;
            const short* bp2 = whh + l * 16384 + tq * 512 + lane * 8;
            v8h bc[4];
            #pragma unroll
            for (int p = 0; p < 3; p++)
                bc[p] = *(const v8h*)(bp2 + p * 1024);
            const int aoff = mq ? a1off1 : a1off0;
            #pragma unroll
            for (int kb = 0; kb < 16; kb++) {
                if (kb + 3 < 16)
                    bc[(kb + 3) & 3] = *(const v8h*)(bp2 + (kb + 3) * 1024);
                v8h a = *(const v8h*)&s_x[aoff + kb * 16];
                C2 = MFMA32H(a, bc[kb & 3], C2);
            }
            #pragma unroll
            for (int r = 0; r < 16; r++) cout[r] += sin_hw(C2[r]);
        }
        // no barrier: next GEMM1 reads same x; overwrites after its own barrier
    }

    // ---- store x_out: row = mq*32 + regpat, col = tq*32 + m32 (32-wide) ----
    #pragma unroll
    for (int r = 0; r < 16; r++) {
        const int orow = row0 + mq * 32 + (r & 3) + 8 * (r >> 2) + 4 * h;
        out[orow * 64 + tq * 32 + m32] = cout[r];
    }
}

extern "C" void kernel_launch(void* const* d_in, const int* in_sizes, int n_in,
                              void* d_out, int out_size, void* d_ws, size_t ws_size,
                              hipStream_t stream) {
    const float* pos   = (const float*)d_in[0];
    const float* gfeat = (const float*)d_in[1];
    const float* ffnA  = (const float*)d_in[2];
    const float* W0    = (const float*)d_in[3];
    const float* b0    = (const float*)d_in[4];
    const float* Wh    = (const float*)d_in[5];
    const float* bh    = (const float*)d_in[6];
    const float* Whh   = (const float*)d_in[7];
    const float* bhh   = (const float*)d_in[8];
    float* out = (float*)d_out;
    const int N = in_sizes[0] / 3;

    // ws: wh 327680 | whh 81920 | gf 20480 shorts, then bhs 1280 | bhhs 320 f32
    short* wh  = (short*)d_ws;
    short* whh = wh + 327680;
    short* gf  = whh + 81920;
    float* bhs  = (float*)(gf + 20480);     // byte offset 860160, 16B aligned
    float* bhhs = bhs + 1280;

    ffb_pack<<<217, 256, 0, stream>>>(Wh, Whh, ffnA, bh, bhh,
                                      wh, whh, gf, bhs, bhhs);
    ffb_main<<<N / TM, 256, 0, stream>>>(pos, gfeat, W0, b0, bhs, bhhs,
                                         wh, whh, gf, out);
}

// Round 14
// 224.903 us; speedup vs baseline: 1.0292x; 1.0292x over previous
//
#include <hip/hip_runtime.h>

// FFB encoder fused kernel, MI355X (gfx950). Round 24.
//  R23 post-mortem: start-skew flat (155.5 incl ~2.4us skew cost) -> convoy
//  theory falsified. Per-wave accounting: SIMD-layer wall 9.15K cyc, but each
//  wave's layer LATENCY ~27K cyc at ~25% issue density -- the wall is serial
//  PHASE traversal (GEMM1 LDS->MFMA chains, then sin epilogue, then another
//  LDS-latency-exposed head phase). Wins only ever came from shortening
//  phases (fract -8us, bias -1us).
//  R24: DELETE the head phase for 4 of 5 layers. head(l) reads x_{l+1} at
//  byte-identical LDS addresses to GEMM1(l+1)'s a-frags (aoff = mq?a1:a0
//  + kb*16). Fuse head(l-1) into GEMM1(l)'s kb loop: head MFMA reuses the
//  loaded a0/a1; whh streams through a ring-2. Effects: one full phase
//  removed per layer (x4), LDS reads -26% (250->186 b128/wave), +16 MFMAs
//  slotted into GEMM1's matrix stream. Math bit-identical (same kb order
//  into C2, same sin/cout order). Layer-0 GEMM1 peeled; head(4) as tail.
//  Registers: GEMM1-fused = C1 64 + C2 16 AGPR, rings depth-2; worst-phase
//  unified ~148 < 170 (R12/R17 proven clean at this bound).
//  Tripwires: WRITE 32.77MB / FETCH 14.5MB / no spill / absmax 0.0625.
//  If >=150us: phase-latency theory dead -> declare structural ceiling.
//  Kept from R22 (best 152.7): unroll-1 l-loop, bias-in-C1-init, operand-
//  swapped GEMM1/grid, epilogue G-hoist, raw v_sin, packed-b64 stores,
//  32x32x16 head, stride-264 LDS, (256,3), 2 barriers/layer. Skew removed.

#define TM 64
#define XSTRIDE 264
#define GSTRIDE 48
#define K5 0.79577471545947667f         // 5/(2*pi)

typedef __attribute__((ext_vector_type(8))) _Float16 v8h;
typedef __attribute__((ext_vector_type(4))) _Float16 v4h;
typedef __attribute__((ext_vector_type(4))) float v4f;
typedef __attribute__((ext_vector_type(16))) float v16f;

#define MFMA32H(a, b, c) __builtin_amdgcn_mfma_f32_32x32x16_f16(a, b, c, 0, 0, 0)

// Raw v_sin_f32: input in revolutions; HW range reduction covers |u| << 256.
__device__ __forceinline__ float sin_hw(float u) {
    return __builtin_amdgcn_sinf(u);
}

__device__ __forceinline__ short f16s(float x) {      // RNE f32->f16
    _Float16 hh = (_Float16)x;
    return __builtin_bit_cast(short, hh);
}

// ---------------- weight packing ----------------
// wh   f16: [l][kb16][nt8][lane64][8]  (327680 shorts), scaled by K5
// whh  f16: [l][kb16][nt2][lane64][8]  (81920 shorts),  scaled by K5  (32-col tiles)
// gf   f16: [l][nt8][lane64][8]        (20480 shorts),  ffnA*2^(l-1)
// bhs  f32: [l][256]  = bh*K5          (1280 floats)
// bhhs f32: [l][64]   = bhh*K5         (320 floats)
__global__ __launch_bounds__(256) void ffb_pack(
    const float* __restrict__ Wh, const float* __restrict__ Whh,
    const float* __restrict__ ffnA,
    const float* __restrict__ bh, const float* __restrict__ bhh,
    short* __restrict__ wh, short* __restrict__ whh, short* __restrict__ gf,
    float* __restrict__ bhs, float* __restrict__ bhhs)
{
    int t = blockIdx.x * 256 + threadIdx.x;
    if (t < 40960) {                       // (l, kb, nt, lane)
        int lane = t & 63, nt = (t >> 6) & 7, kb = (t >> 9) & 15, l = t >> 13;
        int n = nt * 32 + (lane & 31);
        int k0 = kb * 16 + (lane >> 5) * 8;
        short hs[8];
        #pragma unroll
        for (int jj = 0; jj < 8; jj++)
            hs[jj] = f16s(Wh[(l * 256 + k0 + jj) * 256 + n] * K5);
        *(v8h*)(wh + t * 8) = *(v8h*)hs;
    } else if (t < 51200) {
        int t2 = t - 40960;                // (l, kb16, nt2, lane)
        int lane = t2 & 63, nt = (t2 >> 6) & 1, kb = (t2 >> 7) & 15, l = t2 >> 11;
        int n = nt * 32 + (lane & 31);
        int k0 = kb * 16 + (lane >> 5) * 8;
        short hs[8];
        #pragma unroll
        for (int jj = 0; jj < 8; jj++)
            hs[jj] = f16s(Whh[(l * 256 + k0 + jj) * 64 + n] * K5);
        *(v8h*)(whh + t2 * 8) = *(v8h*)hs;
    } else if (t < 53760) {
        int t3 = t - 51200;                // (l, nt, lane)
        int lane = t3 & 63, nt = (t3 >> 6) & 7, l = t3 >> 9;
        int n = nt * 32 + (lane & 31);
        const float sc = 0.5f * (float)(1 << l);       // 2^(l-1), exact
        short hs[8];
        #pragma unroll
        for (int jj = 0; jj < 8; jj++)
            hs[jj] = f16s(ffnA[(l * 8 + jj) * 256 + n] * sc);
        *(v8h*)(gf + t3 * 8) = *(v8h*)hs;
    } else if (t < 55040) {
        int t4 = t - 53760;
        bhs[t4] = bh[t4] * K5;
    } else if (t < 55360) {
        int t5 = t - 55040;
        bhhs[t5] = bhh[t5] * K5;
    }
}

// ---------------- device helpers ----------------
__device__ __forceinline__ void c1_init(v16f C1[2][2],
                                        const float* __restrict__ bhs,
                                        int l, int w, int h)
{
    // wcol(reg r, h) = w*64 + tt*32 + 8*(r>>2) + 4*h + (r&3)
    const float* bl = bhs + l * 256 + w * 64 + h * 4;
    #pragma unroll
    for (int tt = 0; tt < 2; tt++)
        #pragma unroll
        for (int rq = 0; rq < 4; rq++) {
            v4f b = *(const v4f*)(bl + tt * 32 + rq * 8);
            #pragma unroll
            for (int j = 0; j < 4; j++) {
                C1[0][tt][rq * 4 + j] = b[j];
                C1[1][tt][rq * 4 + j] = b[j];
            }
        }
}

// GEMM1(l) (swapped: wh = A, x = B; ring-2) with OPTIONAL fused head(l-1):
// the head MFMA reuses the a0/a1 frags loaded for C1 (identical addresses).
template <bool FH>
__device__ __forceinline__ void gemm1_fused(
    v16f C1[2][2], float* __restrict__ cout,
    const short* __restrict__ s_xp,
    const short* __restrict__ wh, const short* __restrict__ whh,
    const float* __restrict__ bhhs,
    int l, int w, int lane, int a1off0, int a1off1, int mq, int tq, int m32)
{
    const short* bp = wh + l * 65536 + (2 * w) * 512 + lane * 8;
    v8h rb0[2], rb1[2];
    rb0[0] = *(const v8h*)(bp);
    rb1[0] = *(const v8h*)(bp + 512);
    v16f C2;
    v8h bc[2];
    const short* bp2 = whh + (l - 1) * 16384 + tq * 512 + lane * 8;
    if constexpr (FH) {
        const float b2 = bhhs[(l - 1) * 64 + tq * 32 + m32];
        #pragma unroll
        for (int r = 0; r < 16; r++) C2[r] = b2;
        bc[0] = *(const v8h*)(bp2);
    }
    #pragma unroll
    for (int kb = 0; kb < 16; kb++) {
        if (kb + 1 < 16) {
            rb0[(kb + 1) & 1] = *(const v8h*)(bp + (kb + 1) * 4096);
            rb1[(kb + 1) & 1] = *(const v8h*)(bp + (kb + 1) * 4096 + 512);
        }
        v8h a0 = *(const v8h*)&s_xp[a1off0 + kb * 16];
        v8h a1 = *(const v8h*)&s_xp[a1off1 + kb * 16];
        v8h bc0 = rb0[kb & 1], bc1 = rb1[kb & 1];
        C1[0][0] = MFMA32H(bc0, a0, C1[0][0]);
        C1[0][1] = MFMA32H(bc1, a0, C1[0][1]);
        C1[1][0] = MFMA32H(bc0, a1, C1[1][0]);
        C1[1][1] = MFMA32H(bc1, a1, C1[1][1]);
        if constexpr (FH) {
            if (kb + 1 < 16)
                bc[(kb + 1) & 1] = *(const v8h*)(bp2 + (kb + 1) * 1024);
            C2 = MFMA32H(mq ? a1 : a0, bc[kb & 1], C2);
        }
    }
    if constexpr (FH) {
        #pragma unroll
        for (int r = 0; r < 16; r++) cout[r] += sin_hw(C2[r]);
    }
}

// epilogue: x_{l+1} = sin(C1_biased) + sin(G); G-hoisted; packed b64 stores.
__device__ __forceinline__ void epilogue_x(
    const v16f C1[2][2], short* __restrict__ s_xp,
    const short* __restrict__ s_gp, const short* __restrict__ gf,
    int l, int w, int lane, int m32, int h)
{
    v8h gb0 = *(const v8h*)(gf + ((l * 8 + w * 2 + 0) * 64 + lane) * 8);
    v8h gb1 = *(const v8h*)(gf + ((l * 8 + w * 2 + 1) * 64 + lane) * 8);
    #pragma unroll
    for (int m = 0; m < 2; m++) {
        v8h ga = *(const v8h*)&s_gp[(m * 32 + m32) * GSTRIDE + l * 8];
        v16f Z = {};
        v16f G0 = MFMA32H(gb0, ga, Z);
        v16f G1 = MFMA32H(gb1, ga, Z);
        const int rowb = (m * 32 + m32) * XSTRIDE;
        #pragma unroll
        for (int tt = 0; tt < 2; tt++) {
            const int cb = rowb + w * 64 + tt * 32 + h * 4;
            #pragma unroll
            for (int rq = 0; rq < 4; rq++) {
                v4h pv;
                #pragma unroll
                for (int j = 0; j < 4; j++) {
                    float gv = tt ? G1[rq * 4 + j] : G0[rq * 4 + j];
                    pv[j] = (_Float16)(sin_hw(C1[m][tt][rq * 4 + j])
                                     + sin_hw(gv));
                }
                *(v4h*)(s_xp + cb + rq * 8) = pv;    // 8B aligned
            }
        }
    }
}

// ---------------- main fused kernel ----------------
__global__ __launch_bounds__(256, 3) void ffb_main(
    const float* __restrict__ pos, const float* __restrict__ gfeat,
    const float* __restrict__ W0, const float* __restrict__ b0,
    const float* __restrict__ bhs, const float* __restrict__ bhhs,
    const short* __restrict__ wh, const short* __restrict__ whh,
    const short* __restrict__ gf,
    float* __restrict__ out)
{
    __shared__ __align__(16) short s_x[TM * XSTRIDE];   // f16  (33792 B)
    __shared__ __align__(16) short s_g[TM * GSTRIDE];   // f16  (6144 B)

    const int tid = threadIdx.x;
    const int row0 = blockIdx.x * TM;
    const int lane = tid & 63;
    const int w = tid >> 6;
    const int m32 = lane & 31;
    const int h = lane >> 5;
    const int mq = w >> 1;                 // head-GEMM quadrant row-tile
    const int tq = w & 1;                  // head-GEMM quadrant col-tile

    for (int k2 = tid; k2 < TM * 40; k2 += 256) {
        int r = k2 / 40, f = k2 % 40;
        s_g[r * GSTRIDE + f] = f16s(gfeat[row0 * 40 + k2]);
    }

    // layer 0: x = sin(5*(pos@W0 + b0)); wave w = rows w*16..+15,
    // thread = cols 4*lane..+3; f32 math; packed b64 stores.
    {
        const int c0 = 4 * lane;
        const int r0 = w * 16;
        float w0c[3][4], bq[4];
        #pragma unroll
        for (int j = 0; j < 4; j++) {
            w0c[0][j] = W0[c0 + j];
            w0c[1][j] = W0[256 + c0 + j];
            w0c[2][j] = W0[512 + c0 + j];
            bq[j] = b0[c0 + j];
        }
        #pragma unroll 4
        for (int r = 0; r < 16; r++) {
            const float p0 = pos[(row0 + r0 + r) * 3 + 0];   // wave-uniform
            const float p1 = pos[(row0 + r0 + r) * 3 + 1];
            const float p2 = pos[(row0 + r0 + r) * 3 + 2];
            v4h pv;
            #pragma unroll
            for (int j = 0; j < 4; j++) {
                float d = p0 * w0c[0][j] + p1 * w0c[1][j] + p2 * w0c[2][j] + bq[j];
                pv[j] = (_Float16)sin_hw(d * K5);
            }
            *(v4h*)(s_x + (r0 + r) * XSTRIDE + c0) = pv;
        }
    }
    __syncthreads();

    float cout[16];
    #pragma unroll
    for (int r = 0; r < 16; r++) cout[r] = 0.f;

    const int a1off0 = m32 * XSTRIDE + h * 8;            // x-row tile 0, + kb*16
    const int a1off1 = (32 + m32) * XSTRIDE + h * 8;     // x-row tile 1

    v16f C1[2][2];

    // ---- peeled l = 0 (no predecessor head to fuse) ----
    c1_init(C1, bhs, 0, w, h);
    gemm1_fused<false>(C1, cout, s_x, wh, whh, bhhs,
                       0, w, lane, a1off0, a1off1, mq, tq, m32);
    __syncthreads();   // all waves done reading x_0
    epilogue_x(C1, s_x, s_g, gf, 0, w, lane, m32, h);
    __syncthreads();   // x_1 visible

    // ---- l = 1..4: GEMM1(l) with fused head(l-1) ----
    #pragma unroll 1
    for (int l = 1; l < 5; l++) {
        c1_init(C1, bhs, l, w, h);
        gemm1_fused<true>(C1, cout, s_x, wh, whh, bhhs,
                          l, w, lane, a1off0, a1off1, mq, tq, m32);
        __syncthreads();   // all waves done reading x_l
        epilogue_x(C1, s_x, s_g, gf, l, w, lane, m32, h);
        __syncthreads();   // x_{l+1} visible
    }

    // ---- tail: head(4) on x_5 (ring-2) ----
    {
        const float b2 = bhhs[4 * 64 + tq * 32 + m32];
        v16f C2;
        #pragma unroll
        for (int r = 0; r < 16; r++) C2[r] = b2;
        const short* bp2 = whh + 4 * 16384 + tq * 512 + lane * 8;
        v8h bc[2];
        bc[0] = *(const v8h*)(bp2);
        const int aoff = mq ? a1off1 : a1off0;
        #pragma unroll
        for (int kb = 0; kb < 16; kb++) {
            if (kb + 1 < 16)
                bc[(kb + 1) & 1] = *(const v8h*)(bp2 + (kb + 1) * 1024);
            v8h a = *(const v8h*)&s_x[aoff + kb * 16];
            C2 = MFMA32H(a, bc[kb & 1], C2);
        }
        #pragma unroll
        for (int r = 0; r < 16; r++) cout[r] += sin_hw(C2[r]);
    }

    // ---- store x_out: row = mq*32 + regpat, col = tq*32 + m32 (32-wide) ----
    #pragma unroll
    for (int r = 0; r < 16; r++) {
        const int orow = row0 + mq * 32 + (r & 3) + 8 * (r >> 2) + 4 * h;
        out[orow * 64 + tq * 32 + m32] = cout[r];
    }
}

extern "C" void kernel_launch(void* const* d_in, const int* in_sizes, int n_in,
                              void* d_out, int out_size, void* d_ws, size_t ws_size,
                              hipStream_t stream) {
    const float* pos   = (const float*)d_in[0];
    const float* gfeat = (const float*)d_in[1];
    const float* ffnA  = (const float*)d_in[2];
    const float* W0    = (const float*)d_in[3];
    const float* b0    = (const float*)d_in[4];
    const float* Wh    = (const float*)d_in[5];
    const float* bh    = (const float*)d_in[6];
    const float* Whh   = (const float*)d_in[7];
    const float* bhh   = (const float*)d_in[8];
    float* out = (float*)d_out;
    const int N = in_sizes[0] / 3;

    // ws: wh 327680 | whh 81920 | gf 20480 shorts, then bhs 1280 | bhhs 320 f32
    short* wh  = (short*)d_ws;
    short* whh = wh + 327680;
    short* gf  = whh + 81920;
    float* bhs  = (float*)(gf + 20480);     // byte offset 860160, 16B aligned
    float* bhhs = bhs + 1280;

    ffb_pack<<<217, 256, 0, stream>>>(Wh, Whh, ffnA, bh, bhh,
                                      wh, whh, gf, bhs, bhhs);
    ffb_main<<<N / TM, 256, 0, stream>>>(pos, gfeat, W0, b0, bhs, bhhs,
                                         wh, whh, gf, out);
}